// Round 1
// baseline (209.645 us; speedup 1.0000x reference)
//
#include <hip/hip_runtime.h>
#include <stdint.h>

// out[b,n] = sum_{c,hw} x[b,c,hw]*W_s[n,hw]*W_d[n,c] + W_b[n]
// GEMM: A = x (M=8192, K=3136), B = W_s (N=1024, K=3136), fused c-contraction.
// R11: replace the 2-barrier/vmcnt(0)-drain K-loop (m97-class, ~940 TF) with a
//      counted-vmcnt deep pipeline (T3+T4+T5):
//      - 256x256 tile, BK=32, 8 waves (2M x 4N), per-wave 128x64 output.
//      - LDS = 4-slot ring x (A 16K + B 16K) = 128 KiB; stage tile t+3 while
//        computing tile t -> 2 tiles always in flight -> s_waitcnt vmcnt(8),
//        never vmcnt(0) in the main loop (drain only in the 2-tile tail).
//      - K = 3136/32 = 98 tiles, split-K x2 -> 49 steps/block; grid 256 blocks
//        = exactly 1 block/CU (128 KiB LDS allows 1 block; 8 waves = 2/SIMD).
//      - raw s_barrier + inline-asm waitcnt (NOT __syncthreads, which emits
//        s_waitcnt vmcnt(0) and kills the pipeline); sched_barrier(0) pins the
//        counted wait; s_setprio(1) around each 16-MFMA cluster (T5).
//      - swizzle for 4-chunk (BK=32) rows: slot = q ^ ((row>>1)&3); verified
//        max 2-way bank aliasing (free) on read; DMA dest stays linear with
//        pre-swizzled global source (m173 pattern).

#define K_DIM 3136
#define N_DIM 1024
#define C_DIM 256
#define B_DIM 32
#define M_DIM 8192
#define X_ELEMS (M_DIM * K_DIM)   // 25690112
#define WS_ELEMS (N_DIM * K_DIM)  // 3211264
#define NSTEP 49                  // K-tiles (BK=32) per split-K half

typedef __attribute__((ext_vector_type(8))) short short8v;  // 8 bf16
typedef __attribute__((ext_vector_type(4))) float f32x4;

__device__ __forceinline__ short f2bf(float f) {
  union { float f; unsigned u; } v; v.f = f;
  unsigned r = v.u + 0x7FFFu + ((v.u >> 16) & 1u);
  return (short)(r >> 16);
}

// 16B-per-lane async global->LDS. LDS dest = wave-uniform base + lane*16.
__device__ __forceinline__ void async16(const void* g, void* l) {
  __builtin_amdgcn_global_load_lds(
      (const __attribute__((address_space(1))) unsigned int*)g,
      (__attribute__((address_space(3))) unsigned int*)l, 16, 0, 0);
}

// fp32 -> bf16 for x and W_s (16 elems/thread), plus bias into out.
#define XBLK (X_ELEMS / 4096)                 // 6272
#define CVBLK ((X_ELEMS + WS_ELEMS) / 4096)   // 7056
__global__ __launch_bounds__(256) void convert_bf16_bias(
    const float* __restrict__ x, const float* __restrict__ Ws,
    const float* __restrict__ Wb, short* __restrict__ dst,
    float* __restrict__ out) {
  int bid = blockIdx.x;
  if (bid >= CVBLK) {  // bias: 32768 out elems / 256 = 128 blocks
    int i = (bid - CVBLK) * 256 + threadIdx.x;
    out[i] = Wb[i & (N_DIM - 1)];
    return;
  }
  const float* src;
  short* d;
  size_t base;
  if (bid < XBLK) {
    src = x; d = dst; base = (size_t)bid * 4096;
  } else {
    src = Ws; d = dst + X_ELEMS; base = (size_t)(bid - XBLK) * 4096;
  }
#pragma unroll
  for (int h = 0; h < 2; ++h) {
    size_t i = base + threadIdx.x * 8 + h * 2048;
    f32x4 v0 = __builtin_nontemporal_load((const f32x4*)(src + i));
    f32x4 v1 = __builtin_nontemporal_load((const f32x4*)(src + i) + 1);
    short8v s;
    s[0] = f2bf(v0.x); s[1] = f2bf(v0.y); s[2] = f2bf(v0.z); s[3] = f2bf(v0.w);
    s[4] = f2bf(v1.x); s[5] = f2bf(v1.y); s[6] = f2bf(v1.z); s[7] = f2bf(v1.w);
    *(short8v*)(d + i) = s;
  }
}

// ---- pipelined GEMM ----
// LDS slot s (0..3) at byte s*32768: A[256 rows][32 bf16] then B at +16384.
// Row = 64 B = 4 chunks of 16 B. slot-chunk cs holds global k-chunk
// cs ^ ((row>>1)&3); staging writes linear LDS (DMA), the XOR is applied to
// the per-lane GLOBAL source address; reads XOR back. Max 2-way bank alias.

#define VMCNT(N) asm volatile("s_waitcnt vmcnt(" #N ")" ::: "memory")
#define CBAR() asm volatile("" ::: "memory")
#define BARR() { CBAR(); __builtin_amdgcn_s_barrier(); CBAR(); }

#define STAGEA(T) { char* d_ = sm + (((T) & 3) << 15) + (wv << 10);           \
    const short* g_ = Ag + (size_t)(T) * 32;                                  \
    async16(g_, d_);                                                          \
    async16(g_ + (size_t)128 * K_DIM, d_ + 8192); }

#define STAGEB(T) { char* d_ = sm + (((T) & 3) << 15) + 16384 + (wv << 10);   \
    const short* g_ = Bg + (size_t)(T) * 32;                                  \
    async16(g_, d_);                                                          \
    async16(g_ + (size_t)128 * K_DIM, d_ + 8192); }

#define MFQ(F, AV)                                                            \
  acc[F][0] = __builtin_amdgcn_mfma_f32_16x16x32_bf16(AV, b0, acc[F][0], 0, 0, 0); \
  acc[F][1] = __builtin_amdgcn_mfma_f32_16x16x32_bf16(AV, b1, acc[F][1], 0, 0, 0); \
  acc[F][2] = __builtin_amdgcn_mfma_f32_16x16x32_bf16(AV, b2, acc[F][2], 0, 0, 0); \
  acc[F][3] = __builtin_amdgcn_mfma_f32_16x16x32_bf16(AV, b3, acc[F][3], 0, 0, 0);

// One K-tile = 2 phases. Phase0: stage A(t+3), read b0..b3 + a(fi 0..3), 16
// MFMA. Phase1: stage B(t+3), read a(fi 4..7) (b reg-cached), counted vmcnt,
// 16 MFMA. vmcnt(8) at end of tile t guarantees tile t+1 resident (t+2,t+3
// = 8 loads stay in flight).
#define KTILE(T, STG, VMSTMT)                                                 \
  {                                                                           \
    char* sl = sm + (((T) & 3) << 15);                                        \
    if (STG) STAGEA((T) + 3);                                                 \
    short8v b0 = *(const short8v*)(sl + boff);                                \
    short8v b1 = *(const short8v*)(sl + boff + 1024);                         \
    short8v b2 = *(const short8v*)(sl + boff + 2048);                         \
    short8v b3 = *(const short8v*)(sl + boff + 3072);                         \
    short8v a0 = *(const short8v*)(sl + aoff);                                \
    short8v a1 = *(const short8v*)(sl + aoff + 1024);                         \
    short8v a2 = *(const short8v*)(sl + aoff + 2048);                         \
    short8v a3 = *(const short8v*)(sl + aoff + 3072);                         \
    BARR();                                                                   \
    __builtin_amdgcn_s_setprio(1);                                            \
    MFQ(0, a0) MFQ(1, a1) MFQ(2, a2) MFQ(3, a3)                               \
    __builtin_amdgcn_s_setprio(0);                                            \
    BARR();                                                                   \
    if (STG) STAGEB((T) + 3);                                                 \
    a0 = *(const short8v*)(sl + aoff + 4096);                                 \
    a1 = *(const short8v*)(sl + aoff + 5120);                                 \
    a2 = *(const short8v*)(sl + aoff + 6144);                                 \
    a3 = *(const short8v*)(sl + aoff + 7168);                                 \
    VMSTMT;                                                                   \
    __builtin_amdgcn_sched_barrier(0);                                        \
    BARR();                                                                   \
    __builtin_amdgcn_s_setprio(1);                                            \
    MFQ(4, a0) MFQ(5, a1) MFQ(6, a2) MFQ(7, a3)                               \
    __builtin_amdgcn_s_setprio(0);                                            \
    BARR();                                                                   \
  }

__global__ __launch_bounds__(512, 2) void gemm_fused(
    const short* __restrict__ Abf, const short* __restrict__ Bbf,
    const float* __restrict__ Wd, float* __restrict__ out) {
  __shared__ __align__(16) char sm[131072];  // 128 KiB: 4-slot ring

  const int bid = blockIdx.x;
  const int mt = bid & 31;          // bid%8 == mt%8 -> A-tile pinned to XCD
  const int nt = (bid >> 5) & 3;
  const int z = bid >> 7;           // split-K half: 49 + 49 K-tiles
  const int kt0 = z * NSTEP;

  const int tid = threadIdx.x;
  const int lane = tid & 63;
  const int wv = tid >> 6;          // 0..7
  const int r = lane & 15;
  const int q = lane >> 4;
  const int wm = wv >> 2, wn = wv & 3;  // 2M x 4N wave grid, per-wave 128x64

  // staging: thread covers LDS chunk idx = p*512 + tid (p=0,1);
  // row = p*128 + wv*16 + (lane>>2), cs = lane&3,
  // global chunk = cs ^ ((row>>1)&3) = (lane&3) ^ ((lane>>3)&3).
  const int srow = wv * 16 + (lane >> 2);
  const int sk8 = (lane & 3) ^ ((lane >> 3) & 3);
  const short* Ag = Abf + (size_t)(mt * 256 + srow) * K_DIM + kt0 * 32 + sk8 * 8;
  const short* Bg = Bbf + (size_t)(nt * 256 + srow) * K_DIM + kt0 * 32 + sk8 * 8;

  // fragment-read byte offsets within a slot; frag fi/j adds fi*1024.
  const int swz = (q ^ ((r >> 1) & 3)) << 4;
  const int aoff = (wm * 128 + r) * 64 + swz;
  const int boff = 16384 + (wn * 64 + r) * 64 + swz;

  f32x4 acc[8][4];
#pragma unroll
  for (int i = 0; i < 8; ++i)
#pragma unroll
    for (int j = 0; j < 4; ++j) acc[i][j] = (f32x4)0.0f;

  // prologue: stage tiles 0,1,2 (12 loads); wait tile0 (8 left in flight).
  STAGEA(0) STAGEB(0) STAGEA(1) STAGEB(1) STAGEA(2) STAGEB(2)
  VMCNT(8);
  BARR();

#pragma unroll 1
  for (int t = 0; t < NSTEP - 3; ++t) KTILE(t, 1, VMCNT(8));
  KTILE(NSTEP - 3, 0, VMCNT(4));  // t=46: tiles 47,48 in flight, need 47
  KTILE(NSTEP - 2, 0, VMCNT(0));  // t=47: need 48 (final drain)
  KTILE(NSTEP - 1, 0, (void)0);   // t=48

  // epilogue: out[mt, n] += sum_c acc * W_d[n, c]; A-tile = image mt, c = row.
  // C/D frag layout: col = lane&15 (n), row = q*4 + reg (c).
#pragma unroll
  for (int j = 0; j < 4; ++j) {
    const int n_g = nt * 256 + wn * 64 + 16 * j + r;
    float p = 0.0f;
#pragma unroll
    for (int i = 0; i < 8; ++i) {
      const int c_l = wm * 128 + 16 * i + 4 * q;
      const float4 wd = *(const float4*)(Wd + (size_t)n_g * C_DIM + c_l);
      p += acc[i][j].x * wd.x + acc[i][j].y * wd.y + acc[i][j].z * wd.z +
           acc[i][j].w * wd.w;
    }
    p += __shfl_xor(p, 16, 64);
    p += __shfl_xor(p, 32, 64);
    if (q == 0) atomicAdd(&out[(size_t)mt * N_DIM + n_g], p);
  }
}

extern "C" void kernel_launch(void* const* d_in, const int* in_sizes, int n_in,
                              void* d_out, int out_size, void* d_ws, size_t ws_size,
                              hipStream_t stream) {
  const float* x = (const float*)d_in[0];
  const float* Ws = (const float*)d_in[1];
  const float* Wd = (const float*)d_in[2];
  const float* Wb = (const float*)d_in[3];
  float* out = (float*)d_out;
  short* xbf = (short*)d_ws;  // [X_ELEMS] bf16 x, then [WS_ELEMS] bf16 W_s

  convert_bf16_bias<<<dim3(CVBLK + 128), dim3(256), 0, stream>>>(x, Ws, Wb, xbf, out);
  gemm_fused<<<dim3(32 * 4 * 2), dim3(512), 0, stream>>>(xbf, xbf + X_ELEMS, Wd, out);
}